// Round 6
// baseline (359.100 us; speedup 1.0000x reference)
//
#include <hip/hip_runtime.h>
#include <hip/hip_bf16.h>
#include <cstdint>

#define B_ 2
#define S_ 2048
#define E_ 2048
#define H_ 16
#define KV_ 4
#define HD_ 128
#define BS_ (B_*S_)
#define QKV_LD 3072
#define SM_SCALE 0.08838834764831845f   // 1/sqrt(128)
#define SC_LOG2E 0.1275424488538497f    // SM_SCALE * log2(e)

typedef __attribute__((ext_vector_type(8))) __bf16 bf16x8;
typedef __attribute__((ext_vector_type(4))) float  floatx4;

__device__ __forceinline__ unsigned short f2bf(float f) {
  union { float f; unsigned u; } v; v.f = f;
  unsigned r = v.u + 0x7fffu + ((v.u >> 16) & 1u);   // RTNE
  return (unsigned short)(r >> 16);
}
__device__ __forceinline__ float bf2f(unsigned short u) {
  union { unsigned u; float f; } v; v.u = ((unsigned)u) << 16; return v.f;
}
__device__ __forceinline__ unsigned pack_bf16x2(float a, float b) {
  union { __hip_bfloat162 h; unsigned u; } v;
  v.h = __float22bfloat162_rn(make_float2(a, b));
  return v.u;
}

__device__ __forceinline__ void async_cp16(const void* g, void* l) {
  __builtin_amdgcn_global_load_lds(
      (const __attribute__((address_space(1))) void*)g,
      (__attribute__((address_space(3))) void*)l, 16, 0, 0);
}

// ---------------- fp32 -> bf16 convert (plain) --------------------------------
__global__ __launch_bounds__(256)
void cvt_bf16(const float* __restrict__ src, unsigned short* __restrict__ dst,
              int n4) {
  int idx = blockIdx.x * 256 + threadIdx.x;
  if (idx >= n4) return;
  float4 v = *(const float4*)(src + (size_t)idx * 4);
  ushort4 o;
  o.x = f2bf(v.x); o.y = f2bf(v.y); o.z = f2bf(v.z); o.w = f2bf(v.w);
  *(ushort4*)(dst + (size_t)idx * 4) = o;
}

// ---------------- fp32 W[K][N] -> bf16 W^T[N][K] (transpose convert) ----------
__global__ __launch_bounds__(256)
void cvt_bf16_t(const float* __restrict__ src, unsigned short* __restrict__ dst,
                int N, int dld, int noff) {
  __shared__ float tile[64 * 65];
  const int t = threadIdx.x;
  const int bk = blockIdx.y * 64, bn = blockIdx.x * 64;
  const int r = t >> 2, cg = t & 3;
#pragma unroll
  for (int i = 0; i < 4; ++i) {
    int c = cg * 16 + i * 4;
    float4 v = *(const float4*)(src + (size_t)(bk + r) * N + bn + c);
    tile[r * 65 + c] = v.x; tile[r * 65 + c + 1] = v.y;
    tile[r * 65 + c + 2] = v.z; tile[r * 65 + c + 3] = v.w;
  }
  __syncthreads();
  const int nl = t >> 2, kg = t & 3;
  union { unsigned short u[16]; uint4 q[2]; } o;
#pragma unroll
  for (int j = 0; j < 16; ++j)
    o.u[j] = f2bf(tile[(kg * 16 + j) * 65 + nl]);
  unsigned short* dp = dst + (size_t)(noff + bn + nl) * dld + bk + kg * 16;
  *(uint4*)(dp) = o.q[0];
  *(uint4*)(dp + 8) = o.q[1];
}

// ---------------- RoPE on q (cols 0..2047) and k (cols 2048..2559) ------------
__global__ __launch_bounds__(256)
void rope_kernel(unsigned short* __restrict__ qkv) {
  const int PPR = 1280;
  int idx = blockIdx.x * 256 + threadIdx.x;
  if (idx >= BS_ * PPR) return;
  int row = idx / PPR, p = idx - row * PPR;
  int col = (p < 1024) ? (2 * p) : (2048 + 2 * (p - 1024));
  int d = p & 63;
  int s = row & (S_ - 1);
  float freq = expf(-(float)d * 0.14391156831212787f);
  float ang = (float)s * freq;
  float c = cosf(ang), sn = sinf(ang);
  unsigned short* ptr = qkv + (size_t)row * QKV_LD + col;
  float x1 = bf2f(ptr[0]), x2 = bf2f(ptr[1]);
  ptr[0] = f2bf(x1 * c - x2 * sn);
  ptr[1] = f2bf(x1 * sn + x2 * c);
}

// ---------------- V transpose: qkv V-cols -> vt[g][hd][s] ---------------------
__global__ __launch_bounds__(256)
void vtrans_kernel(const unsigned short* __restrict__ qkv,
                   unsigned short* __restrict__ vt) {
  __shared__ unsigned short tile[64 * 72];
  const int tid = threadIdx.x;
  const int s0 = blockIdx.x * 64;
  const int g = blockIdx.y >> 1;
  const int hh = (blockIdx.y & 1) * 64;
  const int b = g >> 2, kvh = g & 3;
#pragma unroll
  for (int i = 0; i < 2; ++i) {
    int chunk = tid + i * 256;
    int r = chunk >> 3, c = (chunk & 7) * 8;
    uint4 v = *(const uint4*)(qkv + (size_t)(b * S_ + s0 + r) * QKV_LD + 2560 + kvh * HD_ + hh + c);
    *(uint4*)(tile + r * 72 + c) = v;
  }
  __syncthreads();
#pragma unroll
  for (int i = 0; i < 2; ++i) {
    int chunk = tid + i * 256;
    int hdr = chunk >> 3, sc = (chunk & 7) * 8;
    union { unsigned short u[8]; uint4 v; } t;
#pragma unroll
    for (int j = 0; j < 8; ++j) t.u[j] = tile[(sc + j) * 72 + hdr];
    *(uint4*)(vt + (size_t)(g * HD_ + hh + hdr) * S_ + s0 + sc) = t.v;
  }
}

// ---------------- bf16 GEMM, 256x256 tile, BK=64, 8-phase (m201 template) -----
// C = A[M][K] * BT[N][K]^T. 512 threads = 8 waves (2M x 4N), per-wave out
// 128x64. LDS 128KB: 2 dbuf x (A 256x64 + B 256x64) bf16.
// Phases per K-tile: (A1,B0) (A1,B1) (A0,B1) (A0,B0); frags reused in regs ->
// ds_reads/phase = 12,4,8,0. Stages: ph0 (kt+1).A0, ph1 (kt+1).B1 (other buf,
// always safe); ph2 (kt+2).B0, ph3 (kt+2).A1 (current buf, regions dead after
// their last-read phase + barrier). vmcnt(4) once per K-tile (ph3 end):
// incoming tile's 8 loads landed, 2 half-tiles stay in flight.
// LDS swizzle: row rotation — slot s of row r holds col-group (s-r)&7 (16B
// groups), staged via pre-swizzled global source (linear LDS dest), read via
// slot = (grp + row)&7. setprio(1) around each 16-MFMA cluster (T5).
// R6 hardening: drain vmcnt(0) after the K-loop (no in-flight LDS writes at
// s_endpgm -> cannot corrupt a successor workgroup's LDS on the same CU).
template<bool OUT_BF16>
__global__ __launch_bounds__(512, 2)
void gemm8(const unsigned short* __restrict__ A,
           const unsigned short* __restrict__ BT,
           void* __restrict__ C, int M, int N, int K) {
  __shared__ unsigned short Ash[2][256 * 64];
  __shared__ unsigned short Bsh[2][256 * 64];
  const int tid = threadIdx.x, l = tid & 63, w = tid >> 6;
  const int l16 = l & 15, l4 = l >> 4;
  const int w2 = w >> 2, w3 = w & 3;

  // bijective XCD swizzle (nwg % 8 == 0 at both call sites)
  const int ntn = (int)gridDim.x;
  const int nwg = (int)(gridDim.x * gridDim.y);
  const int orig = (int)blockIdx.y * ntn + (int)blockIdx.x;
  const int cpx = nwg >> 3;
  const int swz = (orig & 7) * cpx + (orig >> 3);
  const int bm = (swz / ntn) * 256, bn = (swz % ntn) * 256;

  // staging source (per-thread): row bm+srow, col-group pre-swizzled
  const int srow = tid >> 3;                      // 0..63 (row within round)
  const int sgrp = ((tid & 7) - (tid >> 3)) & 7;  // source col-group
  const unsigned short* Asrc = A  + (size_t)(bm + srow) * K + sgrp * 8;
  const unsigned short* Bsrc = BT + (size_t)(bn + srow) * K + sgrp * 8;
  const int ldst = w * 512;                       // wave base (ushort) in round

#define STAGE_A8(buf, H, kb) do { \
    async_cp16(Asrc + (size_t)((H) * 128) * K + (kb),      &Ash[buf][(H) * 8192 + ldst]); \
    async_cp16(Asrc + (size_t)((H) * 128 + 64) * K + (kb), &Ash[buf][(H) * 8192 + 4096 + ldst]); \
  } while (0)
#define STAGE_B8(buf, H, kb) do { \
    async_cp16(Bsrc + (size_t)((H) * 128) * K + (kb),      &Bsh[buf][(H) * 8192 + ldst]); \
    async_cp16(Bsrc + (size_t)((H) * 128 + 64) * K + (kb), &Bsh[buf][(H) * 8192 + 4096 + ldst]); \
  } while (0)
#define BAR8() __builtin_amdgcn_s_barrier()
#define VMCNT4() asm volatile("s_waitcnt vmcnt(4)" ::: "memory")

  // ds_read slots (rotation by row; row ≡ l16 mod 8 for all fragments)
  const int s0 = ((l4 + l16) & 7) * 8;       // ks = 0
  const int s1 = ((l4 + l16 + 4) & 7) * 8;   // ks = 1
  const int arb = w2 * 64 + l16;             // A row base (+ mh*128 + m*16)
  const int brb = w3 * 32 + l16;             // B row base (+ nh*128 + n*16)

  const int nkt = K >> 6;

  // prologue: issue order B0,A1,A0,B1 (kt0) then B0,A1 (kt1) -> vmcnt(4)
  STAGE_B8(0, 0, 0);
  STAGE_A8(0, 1, 0);
  STAGE_A8(0, 0, 0);
  STAGE_B8(0, 1, 0);
  {
    const int kb1 = (nkt > 1) ? 64 : 0;
    STAGE_B8(1, 0, kb1);
    STAGE_A8(1, 1, kb1);
  }
  VMCNT4(); BAR8();

  floatx4 acc[2][4][2][2] = {};

  for (int kt = 0; kt < nkt; ++kt) {
    const int cur = kt & 1;
    const int kb1 = ((kt + 1 < nkt) ? kt + 1 : nkt - 1) << 6;
    const int kb2 = ((kt + 2 < nkt) ? kt + 2 : nkt - 1) << 6;
    bf16x8 a[4][2], b0[2][2], b1[2][2];

    // ---- phase 0: read A1 + B0; stage (kt+1).A0; MFMA acc[1][*][0][*]
#pragma unroll
    for (int m = 0; m < 4; ++m) {
      const int rA = 128 + arb + m * 16;
      a[m][0] = *(const bf16x8*)(&Ash[cur][rA * 64 + s0]);
      a[m][1] = *(const bf16x8*)(&Ash[cur][rA * 64 + s1]);
    }
#pragma unroll
    for (int n = 0; n < 2; ++n) {
      const int rB = brb + n * 16;
      b0[n][0] = *(const bf16x8*)(&Bsh[cur][rB * 64 + s0]);
      b0[n][1] = *(const bf16x8*)(&Bsh[cur][rB * 64 + s1]);
    }
    STAGE_A8(cur ^ 1, 0, kb1);
    BAR8();
    __builtin_amdgcn_s_setprio(1);
#pragma unroll
    for (int m = 0; m < 4; ++m)
#pragma unroll
      for (int n = 0; n < 2; ++n) {
        acc[1][m][0][n] = __builtin_amdgcn_mfma_f32_16x16x32_bf16(a[m][0], b0[n][0], acc[1][m][0][n], 0, 0, 0);
        acc[1][m][0][n] = __builtin_amdgcn_mfma_f32_16x16x32_bf16(a[m][1], b0[n][1], acc[1][m][0][n], 0, 0, 0);
      }
    __builtin_amdgcn_s_setprio(0);
    BAR8();

    // ---- phase 1: read B1; stage (kt+1).B1; MFMA acc[1][*][1][*]
#pragma unroll
    for (int n = 0; n < 2; ++n) {
      const int rB = 128 + brb + n * 16;
      b1[n][0] = *(const bf16x8*)(&Bsh[cur][rB * 64 + s0]);
      b1[n][1] = *(const bf16x8*)(&Bsh[cur][rB * 64 + s1]);
    }
    STAGE_B8(cur ^ 1, 1, kb1);
    BAR8();
    __builtin_amdgcn_s_setprio(1);
#pragma unroll
    for (int m = 0; m < 4; ++m)
#pragma unroll
      for (int n = 0; n < 2; ++n) {
        acc[1][m][1][n] = __builtin_amdgcn_mfma_f32_16x16x32_bf16(a[m][0], b1[n][0], acc[1][m][1][n], 0, 0, 0);
        acc[1][m][1][n] = __builtin_amdgcn_mfma_f32_16x16x32_bf16(a[m][1], b1[n][1], acc[1][m][1][n], 0, 0, 0);
      }
    __builtin_amdgcn_s_setprio(0);
    BAR8();

    // ---- phase 2: read A0; stage (kt+2).B0; MFMA acc[0][*][1][*]
#pragma unroll
    for (int m = 0; m < 4; ++m) {
      const int rA = arb + m * 16;
      a[m][0] = *(const bf16x8*)(&Ash[cur][rA * 64 + s0]);
      a[m][1] = *(const bf16x8*)(&Ash[cur][rA * 64 + s1]);
    }
    STAGE_B8(cur, 0, kb2);
    BAR8();
    __builtin_amdgcn_s_setprio(1);
#pragma unroll
    for (int m = 0; m < 4; ++m)
#pragma unroll
      for (int n = 0; n < 2; ++n) {
        acc[0][m][1][n] = __builtin_amdgcn_mfma_f32_16x16x32_bf16(a[m][0], b1[n][0], acc[0][m][1][n], 0, 0, 0);
        acc[0][m][1][n] = __builtin_amdgcn_mfma_f32_16x16x32_bf16(a[m][1], b1[n][1], acc[0][m][1][n], 0, 0, 0);
      }
    __builtin_amdgcn_s_setprio(0);
    BAR8();

    // ---- phase 3: no reads; stage (kt+2).A1; MFMA acc[0][*][0][*]; vmcnt(4)
    STAGE_A8(cur, 1, kb2);
    BAR8();
    __builtin_amdgcn_s_setprio(1);
#pragma unroll
    for (int m = 0; m < 4; ++m)
#pragma unroll
      for (int n = 0; n < 2; ++n) {
        acc[0][m][0][n] = __builtin_amdgcn_mfma_f32_16x16x32_bf16(a[m][0], b0[n][0], acc[0][m][0][n], 0, 0, 0);
        acc[0][m][0][n] = __builtin_amdgcn_mfma_f32_16x16x32_bf16(a[m][1], b0[n][1], acc[0][m][0][n], 0, 0, 0);
      }
    __builtin_amdgcn_s_setprio(0);
    VMCNT4();
    BAR8();
  }

  // drain all in-flight global_load_lds before epilogue/endpgm (R6 hardening)
  asm volatile("s_waitcnt vmcnt(0)" ::: "memory");

  // epilogue: C write
#pragma unroll
  for (int mh = 0; mh < 2; ++mh)
#pragma unroll
    for (int m = 0; m < 4; ++m)
#pragma unroll
      for (int nh = 0; nh < 2; ++nh)
#pragma unroll
        for (int n = 0; n < 2; ++n) {
          const int row0 = bm + mh * 128 + w2 * 64 + m * 16 + l4 * 4;
          const int col  = bn + nh * 128 + w3 * 32 + n * 16 + l16;
#pragma unroll
          for (int rr = 0; rr < 4; ++rr) {
            float v = acc[mh][m][nh][n][rr];
            if (OUT_BF16) ((unsigned short*)C)[(size_t)(row0 + rr) * N + col] = f2bf(v);
            else          ((float*)C)[(size_t)(row0 + rr) * N + col] = v;
          }
        }
#undef STAGE_A8
#undef STAGE_B8
#undef BAR8
#undef VMCNT4
}

// ---------------- flash attention v11 (in-block key-segment split) ------------
// (unchanged from round 4 — best measured attention: 83.0 µs)
__global__ __launch_bounds__(512, 2)
void gqa_attention(const unsigned short* __restrict__ qkv,
                   const unsigned short* __restrict__ vt,
                   unsigned short* __restrict__ out) {
  __shared__ unsigned short Ksh[2][2][32 * 128];  // [seg][buf]; swizzled rows
  __shared__ unsigned short Vsh[2][2][128 * 32];  // [seg][buf]; swizzled rows

  const int tid = threadIdx.x, l = tid & 63, wave = tid >> 6;
  const int l16 = l & 15, l4 = l >> 4;
  const int hw = wave & 3, seg = wave >> 2;       // head-in-group, key-segment
  const int g = blockIdx.x, b = g >> 2, kvh = g & 3;
  const int h = kvh * 4 + hw;
  const int y = blockIdx.y;

  const int k_subrow = l >> 4;                      // row within 4-row group
  const int v_subrow = l >> 2;                      // row within 16-row group
  const int gv = (((l & 3) - (l >> 4)) & 3) * 8;    // V swizzled col

  // per-lane staging base pointers (chunk 0); advance by 32-bit offsets
  const unsigned short* kp[2];
  const unsigned short* vp[2];
#pragma unroll
  for (int i = 0; i < 2; ++i) {
    int cc = hw + i * 4;                            // [0,8)
    int krow = 4 * cc + k_subrow;                   // [0,32)
    int gk = (((l & 15) - krow) & 15) * 8;
    kp[i] = qkv + (size_t)(b * S_ + krow) * QKV_LD + 2048 + kvh * HD_ + gk;
    vp[i] = vt + (size_t)(g * HD_ + 16 * cc + v_subrow) * S_ + gv;
  }

  for (int phase = 0; phase < 2; ++phase) {
    const int t = phase ? (63 - y) : y;             // tile of 32 q-rows
    const int qt = t * 32;
    const int nch = t + 1;                          // chunks of 32 keys
    const int c0 = nch >> 1;                        // seg0: [0,c0)  seg1: [c0,nch)
    const int st = nch - c0;                        // lockstep steps

    // Q fragments for both 16-row sub-tiles (both segments load same Q)
    bf16x8 qfA[4], qfB[4];
    {
      const unsigned short* qpA = qkv + (size_t)(b * S_ + qt + l16) * QKV_LD + h * HD_;
      const unsigned short* qpB = qpA + (size_t)16 * QKV_LD;
#pragma unroll
      for (int c = 0; c < 4; ++c) {
        qfA[c] = *(const bf16x8*)(qpA + c * 32 + l4 * 8);
        qfB[c] = *(const bf16x8*)(qpB + c * 32 + l4 * 8);
      }
    }
    asm volatile("s_waitcnt vmcnt(0)" ::: "memory");  // Q landed; stale vm drained
    asm volatile("s_barrier" ::: "memory");           // prev-phase LDS use done

    // prologue: stage own segment's first chunk -> buf 0
    {
      const int ci = (seg == 0) ? 0 : c0;
      const int ko = ci * 32 * QKV_LD, vo = ci * 32;
#pragma unroll
      for (int i = 0; i < 2; ++i) {
        int cc = hw + i * 4;
        async_cp16(kp[i] + ko, &Ksh[seg][0][cc * 512]);
        async_cp16(vp[i] + vo, &Vsh[seg][0][cc * 512]);
      }
    }

    float lsumA = 0.f, lsumB = 0.f;
    floatx4 accA[8] = {}, accB[8] = {};

    for (int step = 0; step < st; ++step) {
      const int cur = step & 1;
      asm volatile("s_barrier" ::: "memory");  // all waves done reading buf[1-cur]
      {
        const int cn = step + 1;
        const int cnext = (seg == 0) ? ((cn < c0) ? cn : 0)
                                     : ((cn < st) ? (c0 + cn) : 0);
        const int ko = cnext * 32 * QKV_LD, vo = cnext * 32;
#pragma unroll
        for (int i = 0; i < 2; ++i) {
          int cc = hw + i * 4;
          async_cp16(kp[i] + ko, &Ksh[seg][cur ^ 1][cc * 512]);
          async_cp16(vp[i] + vo, &Vsh[seg][cur ^ 1][cc * 512]);
        }
      }
      asm volatile("s_waitcnt vmcnt(4)\n\ts_barrier" ::: "memory");

      const bool active = (seg == 1) || (step < c0);
      if (active) {
        const bool tri = (seg == 1) && (step == st - 1);  // diagonal chunk

        floatx4 sA[2] = {}, sB[2] = {};
#pragma unroll
        for (int half = 0; half < 2; ++half) {
          const int krow = half * 16 + l16;
#pragma unroll
          for (int c = 0; c < 4; ++c) {
            const int s = (c * 4 + l4 + l16) & 15;
            bf16x8 kf = *(const bf16x8*)(&Ksh[seg][cur][krow * 128 + s * 8]);
            sA[half] = __builtin_amdgcn_mfma_f32_16x16x32_bf16(kf, qfA[c], sA[half], 0, 0, 0);
            sB[half] = __builtin_amdgcn_mfma_f32_16x16x32_bf16(kf, qfB[c], sB[half], 0, 0, 0);
          }
        }

        float pA[8], pB[8];
#pragma unroll
        for (int half = 0; half < 2; ++half)
#pragma unroll
          for (int r = 0; r < 4; ++r) {
            float vA = fminf(sA[half][r] * SC_LOG2E, 80.f);
            float vB = fminf(sB[half][r] * SC_LOG2E, 80.f);
            if (tri) {
              int kk = half * 16 + l4 * 4 + r;
              if (kk > l16) vA = -3e38f;
              if (half == 1 && (l4 * 4 + r) > l16) vB = -3e38f;
            }
            float eA = exp2f(vA), eB = exp2f(vB);
            pA[half * 4 + r] = eA; lsumA += eA;
            pB[half * 4 + r] = eB; lsumB += eB;
          }

        unsigned a0 = pack_bf16x2(pA[0], pA[1]);
        unsigned a1 = pack_bf16x2(pA[2], pA[3]);
        unsigned a2 = pack_bf16x2(pA[4], pA[5]);
        unsigned a3 = pack_bf16x2(pA[6], pA[7]);
        asm("v_permlane32_swap_b32 %0, %1" : "+v"(a0), "+v"(a2));
        asm("v_permlane16_swap_b32 %0, %1" : "+v"(a0), "+v"(a2));
        asm("v_permlane32_swap_b32 %0, %1" : "+v"(a1), "+v"(a3));
        asm("v_permlane16_swap_b32 %0, %1" : "+v"(a1), "+v"(a3));
        unsigned b0 = pack_bf16x2(pB[0], pB[1]);
        unsigned b1 = pack_bf16x2(pB[2], pB[3]);
        unsigned b2 = pack_bf16x2(pB[4], pB[5]);
        unsigned b3 = pack_bf16x2(pB[6], pB[7]);
        asm("v_permlane32_swap_b32 %0, %1" : "+v"(b0), "+v"(b2));
        asm("v_permlane16_swap_b32 %0, %1" : "+v"(b0), "+v"(b2));
        asm("v_permlane32_swap_b32 %0, %1" : "+v"(b1), "+v"(b3));
        asm("v_permlane16_swap_b32 %0, %1" : "+v"(b1), "+v"(b3));
        union { unsigned w[4]; bf16x8 v8; } punA, punB;
        punA.w[0] = a0; punA.w[1] = a1; punA.w[2] = a2; punA.w[3] = a3;
        punB.w[0] = b0; punB.w[1] = b1; punB.w[2] = b2; punB.w[3] = b3;
        const bf16x8 pfA = punA.v8;
        const bf16x8 pfB = punB.v8;

#pragma unroll
        for (int u = 0; u < 8; ++u) {
          const int row = u * 16 + l16;
          const int s = (l4 + (l16 >> 2)) & 3;
          bf16x8 vf = *(const bf16x8*)(&Vsh[seg][cur][row * 32 + s * 8]);
          accA[u] = __builtin_amdgcn_mfma_f32_16x16x32_bf16(vf, pfA, accA[u], 0, 0, 0);
          accB[u] = __builtin_amdgcn_mfma_f32_16x16x32_bf16(vf, pfB, accB[u], 0, 0, 0);
        }
      }
    }

    // ---- combine seg1 partials into seg0 via the (dead) chunk LDS ----
    asm volatile("s_waitcnt vmcnt(0)" ::: "memory");
    __syncthreads();
    float* combA = (float*)(&Ksh[0][0][0]);
    float* combL = (float*)(&Vsh[0][0][0]);
    if (seg == 1) {
#pragma unroll
      for (int u = 0; u < 8; ++u)
        *(floatx4*)(combA + ((hw * 8 + u) * 64 + l) * 4) = accA[u];
      combL[(hw * 64 + l) * 2]     = lsumA;
      combL[(hw * 64 + l) * 2 + 1] = lsumB;
    }
    __syncthreads();
    if (seg == 0) {
#pragma unroll
      for (int u = 0; u < 8; ++u)
        accA[u] += *(const floatx4*)(combA + ((hw * 8 + u) * 64 + l) * 4);
      lsumA += combL[(hw * 64 + l) * 2];
      lsumB += combL[(hw * 64 + l) * 2 + 1];
    }
    __syncthreads();
    if (seg == 1) {
#pragma unroll
      for (int u = 0; u < 8; ++u)
        *(floatx4*)(combA + ((hw * 8 + u) * 64 + l) * 4) = accB[u];
    }
    __syncthreads();
    if (seg == 0) {
#pragma unroll
      for (int u = 0; u < 8; ++u)
        accB[u] += *(const floatx4*)(combA + ((hw * 8 + u) * 64 + l) * 4);

      lsumA += __shfl_xor(lsumA, 16, 64);
      lsumA += __shfl_xor(lsumA, 32, 64);
      lsumB += __shfl_xor(lsumB, 16, 64);
      lsumB += __shfl_xor(lsumB, 32, 64);
      float invA = 1.0f / lsumA;
      float invB = 1.0f / lsumB;
      unsigned short* opA = out + (size_t)(b * S_ + qt + l16) * 2048 + h * HD_;
      unsigned short* opB = opA + (size_t)16 * 2048;
#pragma unroll
      for (int u = 0; u < 8; ++u) {
        uint2 oA, oB;
        oA.x = pack_bf16x2(accA[u][0] * invA, accA[u][1] * invA);
        oA.y = pack_bf16x2(accA[u][2] * invA, accA[u][3] * invA);
        *(uint2*)(opA + u * 16 + l4 * 4) = oA;
        oB.x = pack_bf16x2(accB[u][0] * invB, accB[u][1] * invB);
        oB.y = pack_bf16x2(accB[u][2] * invB, accB[u][3] * invB);
        *(uint2*)(opB + u * 16 + l4 * 4) = oB;
      }
    }
  }
}

// ---------------- launcher ----------------------------------------------------
extern "C" void kernel_launch(void* const* d_in, const int* in_sizes, int n_in,
                              void* d_out, int out_size, void* d_ws, size_t ws_size,
                              hipStream_t stream) {
  const float* x  = (const float*)d_in[0];
  const float* Wq = (const float*)d_in[1];
  const float* Wk = (const float*)d_in[2];
  const float* Wv = (const float*)d_in[3];
  const float* Wo = (const float*)d_in[4];
  float* out = (float*)d_out;

  char* ws = (char*)d_ws;
  unsigned short* xb    = (unsigned short*)(ws);
  unsigned short* wqkvT = (unsigned short*)(ws + 16777216);
  unsigned short* woT   = (unsigned short*)(ws + 29360128);
  unsigned short* qkv   = (unsigned short*)(ws + 37748736);
  unsigned short* attn  = (unsigned short*)(ws + 62914560);
  unsigned short* vt    = (unsigned short*)(ws);             // aliases xb (dead after GEMM1)

  cvt_bf16<<<(4096 * 2048 / 4 + 255) / 256, 256, 0, stream>>>(x, xb, 4096 * 2048 / 4);
  cvt_bf16_t<<<dim3(32, 32), 256, 0, stream>>>(Wq, wqkvT, 2048, 2048, 0);
  cvt_bf16_t<<<dim3(8, 32),  256, 0, stream>>>(Wk, wqkvT, 512,  2048, 2048);
  cvt_bf16_t<<<dim3(8, 32),  256, 0, stream>>>(Wv, wqkvT, 512,  2048, 2560);
  cvt_bf16_t<<<dim3(32, 32), 256, 0, stream>>>(Wo, woT,  2048, 2048, 0);

  gemm8<true><<<dim3(12, 16), 512, 0, stream>>>(xb, wqkvT, qkv, 4096, 3072, 2048);
  rope_kernel<<<(4096 * 1280 + 255) / 256, 256, 0, stream>>>(qkv);
  vtrans_kernel<<<dim3(32, 16), 256, 0, stream>>>(qkv, vt);
  gqa_attention<<<dim3(8, 32), 512, 0, stream>>>(qkv, vt, attn);
  gemm8<false><<<dim3(8, 16), 512, 0, stream>>>(attn, woT, out, 4096, 2048, 2048);
}